// Round 4
// baseline (17931.122 us; speedup 1.0000x reference)
//
#include <hip/hip_runtime.h>
#include <stdint.h>

#define N_PTS 65536
#define DIMS 6
#define NSAMP 2048
#define NGRP 64
#define EMB 512
#define ROWS (NSAMP*NGRP)
#define EPS_BN 1e-5f

#define FIRST_MODE 0

// ---------------- Threefry-2x32, 20 rounds (JAX-compatible) ----------------
__device__ __forceinline__ void tf2x32(unsigned k0, unsigned k1, unsigned &x0, unsigned &x1) {
  unsigned ks[3] = {k0, k1, k0 ^ k1 ^ 0x1BD11BDAu};
  const unsigned R[8] = {13,15,26,6,17,29,16,24};
  x0 += ks[0]; x1 += ks[1];
#pragma unroll
  for (int g = 0; g < 5; ++g) {
#pragma unroll
    for (int j = 0; j < 4; ++j) {
      unsigned r = R[(g & 1) * 4 + j];
      x0 += x1;
      x1 = (x1 << r) | (x1 >> (32 - r));
      x1 ^= x0;
    }
    x0 += ks[(g + 1) % 3];
    x1 += ks[(g + 2) % 3] + (unsigned)(g + 1);
  }
}

__device__ __forceinline__ int compute_first(unsigned seed) {
  unsigned k0 = 0u, k1 = seed;
  unsigned s0, s1;
#if (FIRST_MODE == 0) || (FIRST_MODE == 1)
  { unsigned a0 = 0u, a1 = 1u; tf2x32(k0, k1, a0, a1); s0 = a0; s1 = a1; }
#else
  { unsigned p0 = 0u, p1 = 2u; tf2x32(k0, k1, p0, p1);
    unsigned q0 = 1u, q1 = 3u; tf2x32(k0, k1, q0, q1);
    s0 = p1; s1 = q1; }
#endif
  unsigned b0 = 0u, b1v = 0u; tf2x32(s0, s1, b0, b1v);
#if (FIRST_MODE == 0) || (FIRST_MODE == 3)
  unsigned bits = b0 ^ b1v;
#else
  unsigned bits = b0;
#endif
  return (int)(bits & 0xFFFFu);
}

// ---------------- FPS geometry ----------------------------------------------
#define FPS_BLK 4
#define FPS_THR 1024
#define FPS_WAVES 64                      // 4 blocks * 16 waves
#define FPS_PPT 16                        // 65536 / 4096 threads
#define FPS_SLOTS ((NSAMP-1)*FPS_WAVES)   // 131008 u64 = ~1 MB

// ---------------- init: zero slots/stats, build xyzw table, first idx ------
__global__ __launch_bounds__(256) void k_init(const float* __restrict__ pts,
    const int* __restrict__ seed_arr, unsigned long long* __restrict__ slot,
    float* __restrict__ stats, float4* __restrict__ xyzw,
    int* __restrict__ sampled) {
  int tid = blockIdx.x * 256 + threadIdx.x;        // 65536 threads
  if (tid < N_PTS) {
    float x = pts[tid*6], y = pts[tid*6+1], z = pts[tid*6+2];
    float p2 = __fadd_rn(__fadd_rn(__fmul_rn(x,x), __fmul_rn(y,y)), __fmul_rn(z,z));
    xyzw[tid] = make_float4(x, y, z, p2);
  }
  for (int k = tid; k < FPS_SLOTS; k += 65536) slot[k] = 0ull;
  if (tid < 4*EMB) stats[tid] = 0.f;
  if (tid == 0) sampled[0] = compute_first((unsigned)seed_arr[0]);
}

// ---------------- FPS: wave-autonomous all-to-all, no intra-block sync ------
// 64 waves; per iter each wave: butterfly-reduce own best -> lane0 stores to
// slot[it*64+wave] -> lane L polls slot[it*64+L] -> butterfly over 64 values
// gives every lane the winner in registers. Zero __syncthreads in the loop.
// Packed key (dist_bits<<32 | ~idx) is provably nonzero => value is its own
// ready flag; RELAXED agent-scope atomics suffice.
__global__ __launch_bounds__(FPS_THR) void k_fps(const float4* __restrict__ xyzw,
    unsigned long long* __restrict__ slot, int* __restrict__ sampled) {
  const int T = blockIdx.x * FPS_THR + threadIdx.x;   // 0..4095
  const int gw = T >> 6;                              // global wave 0..63
  const int lane = T & 63;
  float px[FPS_PPT], py[FPS_PPT], pz[FPS_PPT], pd[FPS_PPT];
#pragma unroll
  for (int i = 0; i < FPS_PPT; ++i) {
    float4 p = xyzw[T + 4096*i];
    px[i] = p.x; py[i] = p.y; pz[i] = p.z; pd[i] = __builtin_inff();
  }
  int last = sampled[0];
  for (int it = 0; it < NSAMP-1; ++it) {
    float4 cc = xyzw[last];
    unsigned long long best = 1ull;   // nonzero floor
#pragma unroll
    for (int i = 0; i < FPS_PPT; ++i) {
      int j = T + 4096*i;
      if (j == last) {
        pd[i] = -__builtin_inff();
      } else {
        float dx = __fsub_rn(px[i], cc.x);
        float dy = __fsub_rn(py[i], cc.y);
        float dz = __fsub_rn(pz[i], cc.z);
        float d = __fadd_rn(__fadd_rn(__fmul_rn(dx,dx), __fmul_rn(dy,dy)), __fmul_rn(dz,dz));
        pd[i] = fminf(pd[i], d);
      }
      if (pd[i] >= 0.f) {
        unsigned long long pk = ((unsigned long long)__float_as_uint(pd[i]) << 32)
                              | (unsigned long long)(0xFFFFFFFFu - (unsigned)j);
        best = best > pk ? best : pk;
      }
    }
#pragma unroll
    for (int off = 32; off >= 1; off >>= 1) {
      unsigned long long o = __shfl_xor(best, off, 64);
      best = best > o ? best : o;
    }
    if (lane == 0)
      __hip_atomic_store(&slot[it*FPS_WAVES + gw], best,
                         __ATOMIC_RELAXED, __HIP_MEMORY_SCOPE_AGENT);
    const unsigned long long* p = &slot[it*FPS_WAVES + lane];
    unsigned long long v = __hip_atomic_load(p, __ATOMIC_RELAXED, __HIP_MEMORY_SCOPE_AGENT);
    while (v == 0ull)
      v = __hip_atomic_load(p, __ATOMIC_RELAXED, __HIP_MEMORY_SCOPE_AGENT);
#pragma unroll
    for (int off = 32; off >= 1; off >>= 1) {
      unsigned long long o = __shfl_xor(v, off, 64);
      v = v > o ? v : o;
    }
    int win = (int)(0xFFFFFFFFu - (unsigned)(v & 0xFFFFFFFFull));
    if (T == 0) sampled[it+1] = win;   // plain store; consumed after kernel end
    last = win;
  }
}

// ---------------- grouping: radix-select top-64 nearest per centroid -------
#define GB_BINS 8192
#define GB_CAND 512

__global__ __launch_bounds__(256) void k_group(const float4* __restrict__ xyzw,
    const int* __restrict__ sampled, int* __restrict__ groups) {
  const int s = blockIdx.x, t = threadIdx.x;
  __shared__ unsigned hist[GB_BINS];
  __shared__ unsigned psum[256];
  __shared__ float csh[4];
  __shared__ int sB, sBefore;
  __shared__ unsigned outcnt, candcnt;
  __shared__ unsigned candK[GB_CAND];
  __shared__ int candI[GB_CAND];
  if (t == 0) {
    float4 c = xyzw[sampled[s]];
    csh[0]=c.x; csh[1]=c.y; csh[2]=c.z; csh[3]=c.w;
    outcnt = 0u; candcnt = 0u;
  }
  for (int k = t; k < GB_BINS; k += 256) hist[k] = 0u;
  __syncthreads();
  const float cx=csh[0], cy=csh[1], cz=csh[2], c2=csh[3];
  for (int i = 0; i < N_PTS/256; ++i) {
    int j = i*256 + t;
    float4 p = xyzw[j];
    float dot = __fadd_rn(__fadd_rn(__fmul_rn(cx,p.x),__fmul_rn(cy,p.y)),__fmul_rn(cz,p.z));
    float d = __fsub_rn(__fadd_rn(c2, p.w), __fmul_rn(2.0f, dot));
    unsigned kb = __float_as_uint(d);
    kb ^= ((unsigned)((int)kb >> 31)) | 0x80000000u;
    atomicAdd(&hist[kb >> 19], 1u);
  }
  __syncthreads();
  unsigned chunk = 0u;
  for (int k = 0; k < 32; ++k) chunk += hist[t*32 + k];
  psum[t] = chunk;
  __syncthreads();
  for (int off = 1; off < 256; off <<= 1) {
    unsigned v = (t >= off) ? psum[t - off] : 0u;
    __syncthreads();
    psum[t] += v;
    __syncthreads();
  }
  unsigned inc = psum[t], before = inc - chunk;
  if (before < NGRP && inc >= NGRP) {
    unsigned c = before;
    for (int k = 0; k < 32; ++k) {
      unsigned nb = hist[t*32 + k];
      if (c + nb >= NGRP) { sB = t*32 + k; sBefore = (int)c; break; }
      c += nb;
    }
  }
  __syncthreads();
  const unsigned B = (unsigned)sB;
  const int bef = sBefore;
  for (int i = 0; i < N_PTS/256; ++i) {
    int j = i*256 + t;
    float4 p = xyzw[j];
    float dot = __fadd_rn(__fadd_rn(__fmul_rn(cx,p.x),__fmul_rn(cy,p.y)),__fmul_rn(cz,p.z));
    float d = __fsub_rn(__fadd_rn(c2, p.w), __fmul_rn(2.0f, dot));
    unsigned kb = __float_as_uint(d);
    kb ^= ((unsigned)((int)kb >> 31)) | 0x80000000u;
    unsigned bin = kb >> 19;
    if (bin < B) {
      unsigned pos = atomicAdd(&outcnt, 1u);
      groups[s*NGRP + pos] = j;
    } else if (bin == B) {
      unsigned ci = atomicAdd(&candcnt, 1u);
      if (ci < GB_CAND) { candK[ci] = kb; candI[ci] = j; }
    }
  }
  __syncthreads();
  int M = candcnt < GB_CAND ? (int)candcnt : GB_CAND;
  int need = NGRP - bef;
  for (int c = t; c < M; c += 256) {
    unsigned mk = candK[c]; int mi = candI[c];
    int rank = 0;
    for (int q = 0; q < M; ++q) {
      unsigned qk = candK[q];
      rank += (qk < mk || (qk == mk && candI[q] < mi)) ? 1 : 0;
    }
    if (rank < need) {
      unsigned pos = atomicAdd(&outcnt, 1u);
      groups[s*NGRP + pos] = candI[c];
    }
  }
  __syncthreads();
  if (t == 0) {
    while (outcnt < NGRP) { groups[s*NGRP + outcnt] = 0; ++outcnt; }
  }
}

// ---------------- stats for bn1 (Y1 never stored) ---------------------------
__global__ __launch_bounds__(EMB) void k_stats1(const float* __restrict__ pts,
    const int* __restrict__ sampled, const int* __restrict__ groups,
    const float* __restrict__ W1, const float* __restrict__ b1,
    float* __restrict__ gsum, float* __restrict__ gss) {
  const int s = blockIdx.x, t = threadIdx.x;
  __shared__ float cf[DIMS];
  __shared__ float feat[NGRP*12];
  if (t < DIMS) cf[t] = pts[sampled[s]*6 + t];
  __syncthreads();
  if (t < NGRP) {
    int g = groups[s*NGRP + t];
#pragma unroll
    for (int k = 0; k < DIMS; ++k) {
      float v = pts[g*6 + k];
      feat[t*12 + k] = v - cf[k];
      feat[t*12 + 6 + k] = v;
    }
  }
  __syncthreads();
  float w[12];
#pragma unroll
  for (int k = 0; k < 12; ++k) w[k] = W1[k*EMB + t];
  float b = b1[t];
  float sum = 0.f, ss = 0.f;
  for (int r = 0; r < NGRP; ++r) {
    float y = b;
#pragma unroll
    for (int k = 0; k < 12; ++k) y += feat[r*12+k] * w[k];
    sum += y; ss += y*y;
  }
  atomicAdd(&gsum[t], sum);
  atomicAdd(&gss[t], ss);
}

// ---------------- bn finalize: a = scale*rsqrt(var+eps), c = bias - a*mean --
__global__ __launch_bounds__(EMB) void k_finalize(const float* __restrict__ gsum,
    const float* __restrict__ gss, const float* __restrict__ scale,
    const float* __restrict__ bias, float* __restrict__ ac) {
  int c = threadIdx.x;
  float inv = 1.f / (float)ROWS;
  float mean = gsum[c] * inv;
  float var = gss[c] * inv - mean*mean;
  var = var < 0.f ? 0.f : var;
  float a = scale[c] * rsqrtf(var + EPS_BN);
  ac[c] = a; ac[EMB + c] = bias[c] - mean * a;
}

// ---------------- fused gather+GEMM1+bn1+relu+GEMM2+stats2+select-pool ------
__global__ __launch_bounds__(EMB) void k_mlp(const float* __restrict__ pts,
    const int* __restrict__ sampled, const int* __restrict__ groups,
    const float* __restrict__ W1, const float* __restrict__ b1,
    const float* __restrict__ ac1, const float* __restrict__ W2,
    const float* __restrict__ b2, const float* __restrict__ scale2,
    float* __restrict__ gsum, float* __restrict__ gss,
    float* __restrict__ y2sel) {
  const int s = blockIdx.x, t = threadIdx.x;
  extern __shared__ float sm[];
  float* feat = sm;                 // 768
  float* cf   = sm + 768;           // 8
  float* red  = sm + 776;           // 2048
  float* h1   = sm + 2824;          // 64*512
  if (t < DIMS) cf[t] = pts[sampled[s]*6 + t];
  __syncthreads();
  if (t < NGRP) {
    int g = groups[s*NGRP + t];
#pragma unroll
    for (int k = 0; k < DIMS; ++k) {
      float v = pts[g*6 + k];
      feat[t*12+k]   = v - cf[k];
      feat[t*12+6+k] = v;
    }
  }
  __syncthreads();
  {
    float w[12];
#pragma unroll
    for (int k = 0; k < 12; ++k) w[k] = W1[k*EMB + t];
    float b = b1[t], a1 = ac1[t], c1 = ac1[EMB + t];
    for (int r = 0; r < NGRP; ++r) {
      float y = b;
#pragma unroll
      for (int k = 0; k < 12; ++k) y += feat[r*12+k] * w[k];
      float hv = a1*y + c1;
      h1[r*EMB + t] = hv > 0.f ? hv : 0.f;
    }
  }
  __syncthreads();
  const int lane = t & 63, wid = t >> 6;
  float acc[8][8];
  {
    float4 blo = *(const float4*)&b2[lane*8];
    float4 bhi = *(const float4*)&b2[lane*8 + 4];
    float b2r[8] = {blo.x, blo.y, blo.z, blo.w, bhi.x, bhi.y, bhi.z, bhi.w};
#pragma unroll
    for (int i = 0; i < 8; ++i)
#pragma unroll
      for (int j = 0; j < 8; ++j) acc[i][j] = b2r[j];
  }
  const float* h1r = h1 + (wid*8)*EMB;
  for (int k = 0; k < EMB; ++k) {
    float4 wlo = *(const float4*)&W2[k*EMB + lane*8];
    float4 whi = *(const float4*)&W2[k*EMB + lane*8 + 4];
    float wv[8] = {wlo.x, wlo.y, wlo.z, wlo.w, whi.x, whi.y, whi.z, whi.w};
    float hv[8];
#pragma unroll
    for (int i = 0; i < 8; ++i) hv[i] = h1r[i*EMB + k];
#pragma unroll
    for (int i = 0; i < 8; ++i)
#pragma unroll
      for (int j = 0; j < 8; ++j) acc[i][j] += hv[i] * wv[j];
  }
  float psum[8], pss[8], pmax[8], pmin[8];
#pragma unroll
  for (int j = 0; j < 8; ++j) {
    float sv=0.f, ssv=0.f, mx=-__builtin_inff(), mn=__builtin_inff();
#pragma unroll
    for (int i = 0; i < 8; ++i) {
      float v = acc[i][j];
      sv += v; ssv += v*v;
      mx = fmaxf(mx, v); mn = fminf(mn, v);
    }
    psum[j]=sv; pss[j]=ssv; pmax[j]=mx; pmin[j]=mn;
  }
  float* rsum = red; float* rss = red+512; float* rmx = red+1024; float* rmn = red+1536;
  for (int w = 0; w < 8; ++w) {
    if (wid == w) {
#pragma unroll
      for (int j = 0; j < 8; ++j) {
        int c = lane*8 + j;
        if (w == 0) { rsum[c]=psum[j]; rss[c]=pss[j]; rmx[c]=pmax[j]; rmn[c]=pmin[j]; }
        else { rsum[c]+=psum[j]; rss[c]+=pss[j];
               rmx[c]=fmaxf(rmx[c],pmax[j]); rmn[c]=fminf(rmn[c],pmin[j]); }
      }
    }
    __syncthreads();
  }
  atomicAdd(&gsum[t], rsum[t]);
  atomicAdd(&gss[t], rss[t]);
  y2sel[s*EMB + t] = (scale2[t] >= 0.f) ? rmx[t] : rmn[t];
}

// ---------------- epilogue: bn2+relu on pooled extremum ---------------------
__global__ __launch_bounds__(256) void k_out(const float* __restrict__ y2sel,
    const float* __restrict__ ac2, float* __restrict__ out) {
  int i = blockIdx.x*256 + threadIdx.x;
  int c = i & (EMB-1);
  float a = ac2[c], cc = ac2[EMB + c];
  float v = a*y2sel[i] + cc;
  out[i] = v > 0.f ? v : 0.f;
}

extern "C" void kernel_launch(void* const* d_in, const int* in_sizes, int n_in,
                              void* d_out, int out_size, void* d_ws, size_t ws_size,
                              hipStream_t stream) {
  const float* pts    = (const float*)d_in[0];
  const float* W1     = (const float*)d_in[1];
  const float* b1     = (const float*)d_in[2];
  const float* scale1 = (const float*)d_in[3];
  const float* bias1  = (const float*)d_in[4];
  const float* W2     = (const float*)d_in[5];
  const float* b2     = (const float*)d_in[6];
  const float* scale2 = (const float*)d_in[7];
  const float* bias2  = (const float*)d_in[8];
  const int*   seed   = (const int*)d_in[9];
  float* out = (float*)d_out;

  char* ws = (char*)d_ws;
  int*    sampled = (int*)(ws);
  int*    groups  = (int*)(ws + 8192);
  float4* xyzw    = (float4*)(ws + 532480);
  float*  stats   = (float*)(ws + 1581056);
  float* gsum1 = stats, *gss1 = stats+512, *gsum2 = stats+1024, *gss2 = stats+1536;
  float*  ac1     = (float*)(ws + 1589248);
  float*  ac2     = (float*)(ws + 1593344);
  float*  y2sel   = (float*)(ws + 1597440);
  // slot aliases y2sel (disjoint lifetime): 131008 u64 = ~1 MB < 4 MB region
  unsigned long long* slot = (unsigned long long*)(ws + 1597440);

  k_init<<<256, 256, 0, stream>>>(pts, seed, slot, stats, xyzw, sampled);
  k_fps<<<FPS_BLK, FPS_THR, 0, stream>>>(xyzw, slot, sampled);
  k_group<<<NSAMP, 256, 0, stream>>>(xyzw, sampled, groups);
  k_stats1<<<NSAMP, EMB, 0, stream>>>(pts, sampled, groups, W1, b1, gsum1, gss1);
  k_finalize<<<1, EMB, 0, stream>>>(gsum1, gss1, scale1, bias1, ac1);
  size_t mlp_lds = (size_t)(2824 + 64*EMB) * sizeof(float);
  k_mlp<<<NSAMP, EMB, mlp_lds, stream>>>(pts, sampled, groups, W1, b1, ac1,
                                         W2, b2, scale2, gsum2, gss2, y2sel);
  k_finalize<<<1, EMB, 0, stream>>>(gsum2, gss2, scale2, bias2, ac2);
  k_out<<<(out_size+255)/256, 256, 0, stream>>>(y2sel, ac2, out);
}

// Round 5
// 6865.617 us; speedup vs baseline: 2.6117x; 2.6117x over previous
//
#include <hip/hip_runtime.h>
#include <stdint.h>

#define N_PTS 65536
#define DIMS 6
#define NSAMP 2048
#define NGRP 64
#define EMB 512
#define ROWS (NSAMP*NGRP)
#define EPS_BN 1e-5f

#define FIRST_MODE 0

// ---------------- Threefry-2x32, 20 rounds (JAX-compatible) ----------------
__device__ __forceinline__ void tf2x32(unsigned k0, unsigned k1, unsigned &x0, unsigned &x1) {
  unsigned ks[3] = {k0, k1, k0 ^ k1 ^ 0x1BD11BDAu};
  const unsigned R[8] = {13,15,26,6,17,29,16,24};
  x0 += ks[0]; x1 += ks[1];
#pragma unroll
  for (int g = 0; g < 5; ++g) {
#pragma unroll
    for (int j = 0; j < 4; ++j) {
      unsigned r = R[(g & 1) * 4 + j];
      x0 += x1;
      x1 = (x1 << r) | (x1 >> (32 - r));
      x1 ^= x0;
    }
    x0 += ks[(g + 1) % 3];
    x1 += ks[(g + 2) % 3] + (unsigned)(g + 1);
  }
}

__device__ __forceinline__ int compute_first(unsigned seed) {
  unsigned k0 = 0u, k1 = seed;
  unsigned s0, s1;
#if (FIRST_MODE == 0) || (FIRST_MODE == 1)
  { unsigned a0 = 0u, a1 = 1u; tf2x32(k0, k1, a0, a1); s0 = a0; s1 = a1; }
#else
  { unsigned p0 = 0u, p1 = 2u; tf2x32(k0, k1, p0, p1);
    unsigned q0 = 1u, q1 = 3u; tf2x32(k0, k1, q0, q1);
    s0 = p1; s1 = q1; }
#endif
  unsigned b0 = 0u, b1v = 0u; tf2x32(s0, s1, b0, b1v);
#if (FIRST_MODE == 0) || (FIRST_MODE == 3)
  unsigned bits = b0 ^ b1v;
#else
  unsigned bits = b0;
#endif
  return (int)(bits & 0xFFFFu);
}

// ---------------- geometry ---------------------------------------------------
#define FPSB 8                       // FPS blocks (8 slots = one 64B line/iter)
#define MEGA_BLOCKS 256              // 8 FPS + 248 workers; all co-resident
#define FPS_PPT 8                    // 65536 / (8*1024)
#define GB_CAND 512

// ---------------- init -------------------------------------------------------
__global__ __launch_bounds__(256) void k_init(const float* __restrict__ pts,
    const int* __restrict__ seed_arr, unsigned long long* __restrict__ slot,
    float* __restrict__ stats, float4* __restrict__ xyzw,
    int* __restrict__ sampled) {
  int tid = blockIdx.x * 256 + threadIdx.x;        // 65536 threads
  if (tid < N_PTS) {
    float x = pts[tid*6], y = pts[tid*6+1], z = pts[tid*6+2];
    float p2 = __fadd_rn(__fadd_rn(__fmul_rn(x,x), __fmul_rn(y,y)), __fmul_rn(z,z));
    xyzw[tid] = make_float4(x, y, z, p2);
  }
  if (tid < (NSAMP-1)*FPSB) slot[tid] = 0ull;
  if (tid < 4*EMB) stats[tid] = 0.f;
  if (tid >= 1 && tid < NSAMP) sampled[tid] = -1;   // sentinel for workers
  if (tid == 0) sampled[0] = compute_first((unsigned)seed_arr[0]);
}

// ---------------- mega: FPS blocks + group/stats worker blocks ---------------
// FPS (blocks 0..7): R3 leader-wave protocol, but single barrier per iter:
//   double-buffered wred + LDS-spin winner broadcast. Wave 0 is the only
//   global poller per block (8 pollers total, one shared cache line).
// Workers (blocks 8..255): consume sampled[s] progressively (sentinel -1),
//   radix-select top-64 + bn1 stats; fully hidden under FPS. Grid of 256
//   blocks is always co-resident (<= 1-2 blocks/CU) -> no dispatch-order
//   deadlock mode (G16-safe).
__global__ __launch_bounds__(1024) void k_mega(
    const float4* __restrict__ xyzw, const float* __restrict__ pts,
    const float* __restrict__ W1, const float* __restrict__ b1,
    unsigned long long* __restrict__ slot, int* __restrict__ sampled,
    int* __restrict__ groups, float* __restrict__ gsum, float* __restrict__ gss) {
  __shared__ __align__(16) char smraw[44160];
  const int t = threadIdx.x;
  if (blockIdx.x < FPSB) {
    // ------------------ FPS role ------------------
    unsigned long long* wred = (unsigned long long*)smraw;       // [2][16]
    volatile int* winLDS = (volatile int*)(smraw + 256);         // [2]
    const int b = blockIdx.x;
    const int T = b*1024 + t;                                    // 0..8191
    const int lane = t & 63, wid = t >> 6;
    float px[FPS_PPT], py[FPS_PPT], pz[FPS_PPT], pd[FPS_PPT];
#pragma unroll
    for (int i = 0; i < FPS_PPT; ++i) {
      float4 p = xyzw[T + 8192*i];
      px[i] = p.x; py[i] = p.y; pz[i] = p.z; pd[i] = __builtin_inff();
    }
    if (t == 0) { winLDS[0] = -1; winLDS[1] = -1; }
    int last = sampled[0];
    __syncthreads();
    for (int it = 0; it < NSAMP-1; ++it) {
      const int p = it & 1;
      float4 cc = xyzw[last];
      unsigned long long best = 1ull;
#pragma unroll
      for (int i = 0; i < FPS_PPT; ++i) {
        int j = T + 8192*i;
        if (j == last) {
          pd[i] = -__builtin_inff();
        } else {
          float dx = __fsub_rn(px[i], cc.x);
          float dy = __fsub_rn(py[i], cc.y);
          float dz = __fsub_rn(pz[i], cc.z);
          float d = __fadd_rn(__fadd_rn(__fmul_rn(dx,dx), __fmul_rn(dy,dy)), __fmul_rn(dz,dz));
          pd[i] = fminf(pd[i], d);
        }
        if (pd[i] >= 0.f) {
          unsigned long long pk = ((unsigned long long)__float_as_uint(pd[i]) << 32)
                                | (unsigned long long)(0xFFFFFFFFu - (unsigned)j);
          best = best > pk ? best : pk;
        }
      }
#pragma unroll
      for (int off = 32; off >= 1; off >>= 1) {
        unsigned long long o = __shfl_xor(best, off, 64);
        best = best > o ? best : o;
      }
      if (lane == 0) wred[p*16 + wid] = best;
      __syncthreads();
      if (wid == 0) {
        if (lane == 0) winLDS[1-p] = -1;   // safe: all waves past prev spin
        unsigned long long m = wred[p*16 + (lane & 15)];
#pragma unroll
        for (int off = 8; off >= 1; off >>= 1) {
          unsigned long long o = __shfl_xor(m, off, 64);
          m = m > o ? m : o;
        }
        if (lane == 0)
          __hip_atomic_store(&slot[it*FPSB + b], m,
                             __ATOMIC_RELAXED, __HIP_MEMORY_SCOPE_AGENT);
        unsigned long long v = 0ull;
        if (lane < FPSB) {
          const unsigned long long* sp = &slot[it*FPSB + lane];
          v = __hip_atomic_load(sp, __ATOMIC_RELAXED, __HIP_MEMORY_SCOPE_AGENT);
          while (v == 0ull)
            v = __hip_atomic_load(sp, __ATOMIC_RELAXED, __HIP_MEMORY_SCOPE_AGENT);
        }
#pragma unroll
        for (int off = 4; off >= 1; off >>= 1) {
          unsigned long long o = __shfl_xor(v, off, 64);
          v = v > o ? v : o;
        }
        v = __shfl(v, 0, 64);
        int win = (int)(0xFFFFFFFFu - (unsigned)(v & 0xFFFFFFFFull));
        if (lane == 0) {
          if (b == 0)
            __hip_atomic_store((unsigned*)&sampled[it+1], (unsigned)win,
                               __ATOMIC_RELAXED, __HIP_MEMORY_SCOPE_AGENT);
          winLDS[p] = win;
        }
        last = win;
      } else {
        int w = winLDS[p];
        while (w == -1) { __builtin_amdgcn_s_sleep(1); w = winLDS[p]; }
        last = w;
      }
    }
  } else {
    // ------------------ worker role: group + bn1 stats ------------------
    unsigned* hist  = (unsigned*)smraw;              // 8192
    unsigned* scan  = (unsigned*)(smraw + 32768);    // 1024
    unsigned* candK = (unsigned*)(smraw + 36864);    // 512
    int*      candI = (int*)(smraw + 38912);         // 512
    float*    feat  = (float*)(smraw + 40960);       // 768
    float*    cf    = (float*)(smraw + 44032);       // 8
    unsigned* ctl   = (unsigned*)(smraw + 44064);    // outcnt, candcnt
    volatile int* binfo = (volatile int*)(smraw + 44080); // B, bef, sid
    const int wkr = blockIdx.x - FPSB;               // 0..247
    for (int s = wkr; s < NSAMP; s += MEGA_BLOCKS - FPSB) {
      if (t == 0) {
        unsigned v = __hip_atomic_load((const unsigned*)&sampled[s],
                        __ATOMIC_RELAXED, __HIP_MEMORY_SCOPE_AGENT);
        while (v == 0xFFFFFFFFu) {
          __builtin_amdgcn_s_sleep(64);
          v = __hip_atomic_load((const unsigned*)&sampled[s],
                  __ATOMIC_RELAXED, __HIP_MEMORY_SCOPE_AGENT);
        }
        binfo[2] = (int)v;
        ctl[0] = 0u; ctl[1] = 0u;
      }
      for (int k = t; k < 8192; k += 1024) hist[k] = 0u;
      __syncthreads();
      const int sid = binfo[2];
      float4 c4 = xyzw[sid];
      const float cx=c4.x, cy=c4.y, cz=c4.z, c2=c4.w;
      // pass 1: histogram of monotone keys
      for (int i = 0; i < N_PTS/1024; ++i) {
        int j = i*1024 + t;
        float4 p = xyzw[j];
        float dot = __fadd_rn(__fadd_rn(__fmul_rn(cx,p.x),__fmul_rn(cy,p.y)),__fmul_rn(cz,p.z));
        float d = __fsub_rn(__fadd_rn(c2, p.w), __fmul_rn(2.0f, dot));
        unsigned kb = __float_as_uint(d);
        kb ^= ((unsigned)((int)kb >> 31)) | 0x80000000u;
        atomicAdd(&hist[kb >> 19], 1u);
      }
      __syncthreads();
      // scan 1024 chunks of 8 bins
      unsigned ch = 0u;
      for (int k = 0; k < 8; ++k) ch += hist[t*8 + k];
      scan[t] = ch;
      __syncthreads();
      for (int off = 1; off < 1024; off <<= 1) {
        unsigned vv = (t >= off) ? scan[t - off] : 0u;
        __syncthreads();
        scan[t] += vv;
        __syncthreads();
      }
      unsigned inc = scan[t], before = inc - ch;
      if (before < NGRP && inc >= NGRP) {
        unsigned c = before;
        for (int k = 0; k < 8; ++k) {
          unsigned nb = hist[t*8 + k];
          if (c + nb >= NGRP) { binfo[0] = t*8 + k; binfo[1] = (int)c; break; }
          c += nb;
        }
      }
      __syncthreads();
      const unsigned B = (unsigned)binfo[0];
      const int bef = binfo[1];
      // pass 2: emit definite members, collect boundary candidates
      for (int i = 0; i < N_PTS/1024; ++i) {
        int j = i*1024 + t;
        float4 p = xyzw[j];
        float dot = __fadd_rn(__fadd_rn(__fmul_rn(cx,p.x),__fmul_rn(cy,p.y)),__fmul_rn(cz,p.z));
        float d = __fsub_rn(__fadd_rn(c2, p.w), __fmul_rn(2.0f, dot));
        unsigned kb = __float_as_uint(d);
        kb ^= ((unsigned)((int)kb >> 31)) | 0x80000000u;
        unsigned bin = kb >> 19;
        if (bin < B) {
          unsigned pos = atomicAdd(&ctl[0], 1u);
          groups[s*NGRP + pos] = j;
        } else if (bin == B) {
          unsigned ci = atomicAdd(&ctl[1], 1u);
          if (ci < GB_CAND) { candK[ci] = kb; candI[ci] = j; }
        }
      }
      __syncthreads();
      // pass 3: exact (key, idx) rank among boundary candidates
      int M = ctl[1] < GB_CAND ? (int)ctl[1] : GB_CAND;
      int need = NGRP - bef;
      for (int c = t; c < M; c += 1024) {
        unsigned mk = candK[c]; int mi = candI[c];
        int rank = 0;
        for (int q = 0; q < M; ++q) {
          unsigned qk = candK[q];
          rank += (qk < mk || (qk == mk && candI[q] < mi)) ? 1 : 0;
        }
        if (rank < need) {
          unsigned pos = atomicAdd(&ctl[0], 1u);
          groups[s*NGRP + pos] = candI[c];
        }
      }
      __syncthreads();
      if (t == 0) {
        while (ctl[0] < NGRP) { groups[s*NGRP + ctl[0]] = 0; ctl[0]++; }
      }
      __syncthreads();
      // bn1 stats for this sample (Y1 never stored)
      if (t < DIMS) cf[t] = pts[sid*6 + t];
      __syncthreads();
      if (t < NGRP) {
        int g = groups[s*NGRP + t];
#pragma unroll
        for (int k = 0; k < DIMS; ++k) {
          float v = pts[g*6 + k];
          feat[t*12 + k] = v - cf[k];
          feat[t*12 + 6 + k] = v;
        }
      }
      __syncthreads();
      if (t < EMB) {
        float w[12];
#pragma unroll
        for (int k = 0; k < 12; ++k) w[k] = W1[k*EMB + t];
        float b = b1[t];
        float sum = 0.f, ss = 0.f;
        for (int r = 0; r < NGRP; ++r) {
          float y = b;
#pragma unroll
          for (int k = 0; k < 12; ++k) y += feat[r*12+k] * w[k];
          sum += y; ss += y*y;
        }
        atomicAdd(&gsum[t], sum);
        atomicAdd(&gss[t], ss);
      }
      __syncthreads();   // smraw reused next s
    }
  }
}

// ---------------- bn finalize: a = scale*rsqrt(var+eps), c = bias - a*mean --
__global__ __launch_bounds__(EMB) void k_finalize(const float* __restrict__ gsum,
    const float* __restrict__ gss, const float* __restrict__ scale,
    const float* __restrict__ bias, float* __restrict__ ac) {
  int c = threadIdx.x;
  float inv = 1.f / (float)ROWS;
  float mean = gsum[c] * inv;
  float var = gss[c] * inv - mean*mean;
  var = var < 0.f ? 0.f : var;
  float a = scale[c] * rsqrtf(var + EPS_BN);
  ac[c] = a; ac[EMB + c] = bias[c] - mean * a;
}

// ---------------- fused gather+GEMM1+bn1+relu+GEMM2+stats2+select-pool ------
__global__ __launch_bounds__(EMB) void k_mlp(const float* __restrict__ pts,
    const int* __restrict__ sampled, const int* __restrict__ groups,
    const float* __restrict__ W1, const float* __restrict__ b1,
    const float* __restrict__ ac1, const float* __restrict__ W2,
    const float* __restrict__ b2, const float* __restrict__ scale2,
    float* __restrict__ gsum, float* __restrict__ gss,
    float* __restrict__ y2sel) {
  const int s = blockIdx.x, t = threadIdx.x;
  extern __shared__ float sm[];
  float* feat = sm;                 // 768
  float* cf   = sm + 768;           // 8
  float* red  = sm + 776;           // 2048
  float* h1   = sm + 2824;          // 64*512
  if (t < DIMS) cf[t] = pts[sampled[s]*6 + t];
  __syncthreads();
  if (t < NGRP) {
    int g = groups[s*NGRP + t];
#pragma unroll
    for (int k = 0; k < DIMS; ++k) {
      float v = pts[g*6 + k];
      feat[t*12+k]   = v - cf[k];
      feat[t*12+6+k] = v;
    }
  }
  __syncthreads();
  {
    float w[12];
#pragma unroll
    for (int k = 0; k < 12; ++k) w[k] = W1[k*EMB + t];
    float b = b1[t], a1 = ac1[t], c1 = ac1[EMB + t];
    for (int r = 0; r < NGRP; ++r) {
      float y = b;
#pragma unroll
      for (int k = 0; k < 12; ++k) y += feat[r*12+k] * w[k];
      float hv = a1*y + c1;
      h1[r*EMB + t] = hv > 0.f ? hv : 0.f;
    }
  }
  __syncthreads();
  const int lane = t & 63, wid = t >> 6;
  float acc[8][8];
  {
    float4 blo = *(const float4*)&b2[lane*8];
    float4 bhi = *(const float4*)&b2[lane*8 + 4];
    float b2r[8] = {blo.x, blo.y, blo.z, blo.w, bhi.x, bhi.y, bhi.z, bhi.w};
#pragma unroll
    for (int i = 0; i < 8; ++i)
#pragma unroll
      for (int j = 0; j < 8; ++j) acc[i][j] = b2r[j];
  }
  const float* h1r = h1 + (wid*8)*EMB;
  for (int k = 0; k < EMB; ++k) {
    float4 wlo = *(const float4*)&W2[k*EMB + lane*8];
    float4 whi = *(const float4*)&W2[k*EMB + lane*8 + 4];
    float wv[8] = {wlo.x, wlo.y, wlo.z, wlo.w, whi.x, whi.y, whi.z, whi.w};
    float hv[8];
#pragma unroll
    for (int i = 0; i < 8; ++i) hv[i] = h1r[i*EMB + k];
#pragma unroll
    for (int i = 0; i < 8; ++i)
#pragma unroll
      for (int j = 0; j < 8; ++j) acc[i][j] += hv[i] * wv[j];
  }
  float psum[8], pss[8], pmax[8], pmin[8];
#pragma unroll
  for (int j = 0; j < 8; ++j) {
    float sv=0.f, ssv=0.f, mx=-__builtin_inff(), mn=__builtin_inff();
#pragma unroll
    for (int i = 0; i < 8; ++i) {
      float v = acc[i][j];
      sv += v; ssv += v*v;
      mx = fmaxf(mx, v); mn = fminf(mn, v);
    }
    psum[j]=sv; pss[j]=ssv; pmax[j]=mx; pmin[j]=mn;
  }
  float* rsum = red; float* rss = red+512; float* rmx = red+1024; float* rmn = red+1536;
  for (int w = 0; w < 8; ++w) {
    if (wid == w) {
#pragma unroll
      for (int j = 0; j < 8; ++j) {
        int c = lane*8 + j;
        if (w == 0) { rsum[c]=psum[j]; rss[c]=pss[j]; rmx[c]=pmax[j]; rmn[c]=pmin[j]; }
        else { rsum[c]+=psum[j]; rss[c]+=pss[j];
               rmx[c]=fmaxf(rmx[c],pmax[j]); rmn[c]=fminf(rmn[c],pmin[j]); }
      }
    }
    __syncthreads();
  }
  atomicAdd(&gsum[t], rsum[t]);
  atomicAdd(&gss[t], rss[t]);
  y2sel[s*EMB + t] = (scale2[t] >= 0.f) ? rmx[t] : rmn[t];
}

// ---------------- epilogue: bn2+relu on pooled extremum ---------------------
__global__ __launch_bounds__(256) void k_out(const float* __restrict__ y2sel,
    const float* __restrict__ ac2, float* __restrict__ out) {
  int i = blockIdx.x*256 + threadIdx.x;
  int c = i & (EMB-1);
  float a = ac2[c], cc = ac2[EMB + c];
  float v = a*y2sel[i] + cc;
  out[i] = v > 0.f ? v : 0.f;
}

extern "C" void kernel_launch(void* const* d_in, const int* in_sizes, int n_in,
                              void* d_out, int out_size, void* d_ws, size_t ws_size,
                              hipStream_t stream) {
  const float* pts    = (const float*)d_in[0];
  const float* W1     = (const float*)d_in[1];
  const float* b1     = (const float*)d_in[2];
  const float* scale1 = (const float*)d_in[3];
  const float* bias1  = (const float*)d_in[4];
  const float* W2     = (const float*)d_in[5];
  const float* b2     = (const float*)d_in[6];
  const float* scale2 = (const float*)d_in[7];
  const float* bias2  = (const float*)d_in[8];
  const int*   seed   = (const int*)d_in[9];
  float* out = (float*)d_out;

  char* ws = (char*)d_ws;
  int*    sampled = (int*)(ws);
  int*    groups  = (int*)(ws + 8192);
  float4* xyzw    = (float4*)(ws + 532480);
  float*  stats   = (float*)(ws + 1581056);
  float* gsum1 = stats, *gss1 = stats+512, *gsum2 = stats+1024, *gss2 = stats+1536;
  float*  ac1     = (float*)(ws + 1589248);
  float*  ac2     = (float*)(ws + 1593344);
  float*  y2sel   = (float*)(ws + 1597440);
  // slot aliases y2sel (disjoint lifetime): 2047*8 u64 = 131KB < 4MB region
  unsigned long long* slot = (unsigned long long*)(ws + 1597440);

  k_init<<<256, 256, 0, stream>>>(pts, seed, slot, stats, xyzw, sampled);
  k_mega<<<MEGA_BLOCKS, 1024, 0, stream>>>(xyzw, pts, W1, b1, slot, sampled,
                                           groups, gsum1, gss1);
  k_finalize<<<1, EMB, 0, stream>>>(gsum1, gss1, scale1, bias1, ac1);
  size_t mlp_lds = (size_t)(2824 + 64*EMB) * sizeof(float);
  k_mlp<<<NSAMP, EMB, mlp_lds, stream>>>(pts, sampled, groups, W1, b1, ac1,
                                         W2, b2, scale2, gsum2, gss2, y2sel);
  k_finalize<<<1, EMB, 0, stream>>>(gsum2, gss2, scale2, bias2, ac2);
  k_out<<<(out_size+255)/256, 256, 0, stream>>>(y2sel, ac2, out);
}

// Round 6
// 6287.313 us; speedup vs baseline: 2.8520x; 1.0920x over previous
//
#include <hip/hip_runtime.h>
#include <stdint.h>

#define N_PTS 65536
#define DIMS 6
#define NSAMP 2048
#define NGRP 64
#define EMB 512
#define ROWS (NSAMP*NGRP)
#define EPS_BN 1e-5f

#define FIRST_MODE 0

// ---------------- Threefry-2x32, 20 rounds (JAX-compatible) ----------------
__device__ __forceinline__ void tf2x32(unsigned k0, unsigned k1, unsigned &x0, unsigned &x1) {
  unsigned ks[3] = {k0, k1, k0 ^ k1 ^ 0x1BD11BDAu};
  const unsigned R[8] = {13,15,26,6,17,29,16,24};
  x0 += ks[0]; x1 += ks[1];
#pragma unroll
  for (int g = 0; g < 5; ++g) {
#pragma unroll
    for (int j = 0; j < 4; ++j) {
      unsigned r = R[(g & 1) * 4 + j];
      x0 += x1;
      x1 = (x1 << r) | (x1 >> (32 - r));
      x1 ^= x0;
    }
    x0 += ks[(g + 1) % 3];
    x1 += ks[(g + 2) % 3] + (unsigned)(g + 1);
  }
}

__device__ __forceinline__ int compute_first(unsigned seed) {
  unsigned k0 = 0u, k1 = seed;
  unsigned s0, s1;
#if (FIRST_MODE == 0) || (FIRST_MODE == 1)
  { unsigned a0 = 0u, a1 = 1u; tf2x32(k0, k1, a0, a1); s0 = a0; s1 = a1; }
#else
  { unsigned p0 = 0u, p1 = 2u; tf2x32(k0, k1, p0, p1);
    unsigned q0 = 1u, q1 = 3u; tf2x32(k0, k1, q0, q1);
    s0 = p1; s1 = q1; }
#endif
  unsigned b0 = 0u, b1v = 0u; tf2x32(s0, s1, b0, b1v);
#if (FIRST_MODE == 0) || (FIRST_MODE == 3)
  unsigned bits = b0 ^ b1v;
#else
  unsigned bits = b0;
#endif
  return (int)(bits & 0xFFFFu);
}

// ---------------- geometry ---------------------------------------------------
#define FPSB 16                      // FPS blocks (16 slots = two 64B lines/iter)
#define MEGA_BLOCKS 256              // 16 FPS + 240 workers; all co-resident
#define FPS_PPT 4                    // 65536 / (16*1024)
#define GB_CAND 512

// ---------------- init -------------------------------------------------------
__global__ __launch_bounds__(256) void k_init(const float* __restrict__ pts,
    const int* __restrict__ seed_arr, unsigned long long* __restrict__ slot,
    float* __restrict__ stats, float4* __restrict__ xyzw,
    int* __restrict__ sampled) {
  int tid = blockIdx.x * 256 + threadIdx.x;        // 65536 threads
  if (tid < N_PTS) {
    float x = pts[tid*6], y = pts[tid*6+1], z = pts[tid*6+2];
    float p2 = __fadd_rn(__fadd_rn(__fmul_rn(x,x), __fmul_rn(y,y)), __fmul_rn(z,z));
    xyzw[tid] = make_float4(x, y, z, p2);
  }
  if (tid < (NSAMP-1)*FPSB) slot[tid] = 0ull;
  if (tid < 4*EMB) stats[tid] = 0.f;
  if (tid >= 1 && tid < NSAMP) sampled[tid] = -1;   // sentinel for workers
  if (tid == 0) sampled[0] = compute_first((unsigned)seed_arr[0]);
}

// ---------------- mega: FPS blocks + group/stats worker blocks ---------------
// FPS (blocks 0..15): leader-wave protocol, single barrier per iter,
//   double-buffered wred + LDS-spin winner broadcast. Wave 0 is the only
//   global poller per block (16 pollers total, two shared cache lines).
// Workers (blocks 16..255): consume sampled[s] progressively (sentinel -1),
//   radix-select top-64 + bn1 stats; fully hidden under FPS. Grid of 256
//   blocks is always co-resident -> no dispatch-order deadlock (G16-safe).
__global__ __launch_bounds__(1024) void k_mega(
    const float4* __restrict__ xyzw, const float* __restrict__ pts,
    const float* __restrict__ W1, const float* __restrict__ b1,
    unsigned long long* __restrict__ slot, int* __restrict__ sampled,
    int* __restrict__ groups, float* __restrict__ gsum, float* __restrict__ gss) {
  __shared__ __align__(16) char smraw[44160];
  const int t = threadIdx.x;
  if (blockIdx.x < FPSB) {
    // ------------------ FPS role ------------------
    unsigned long long* wred = (unsigned long long*)smraw;       // [2][16]
    volatile int* winLDS = (volatile int*)(smraw + 256);         // [2]
    const int b = blockIdx.x;
    const int T = b*1024 + t;                                    // 0..16383
    const int lane = t & 63, wid = t >> 6;
    float px[FPS_PPT], py[FPS_PPT], pz[FPS_PPT], pd[FPS_PPT];
#pragma unroll
    for (int i = 0; i < FPS_PPT; ++i) {
      float4 p = xyzw[T + 16384*i];
      px[i] = p.x; py[i] = p.y; pz[i] = p.z; pd[i] = __builtin_inff();
    }
    if (t == 0) { winLDS[0] = -1; winLDS[1] = -1; }
    int last = sampled[0];
    __syncthreads();
    for (int it = 0; it < NSAMP-1; ++it) {
      const int p = it & 1;
      float4 cc = xyzw[last];
      unsigned long long best = 1ull;
#pragma unroll
      for (int i = 0; i < FPS_PPT; ++i) {
        int j = T + 16384*i;
        if (j == last) {
          pd[i] = -__builtin_inff();
        } else {
          float dx = __fsub_rn(px[i], cc.x);
          float dy = __fsub_rn(py[i], cc.y);
          float dz = __fsub_rn(pz[i], cc.z);
          float d = __fadd_rn(__fadd_rn(__fmul_rn(dx,dx), __fmul_rn(dy,dy)), __fmul_rn(dz,dz));
          pd[i] = fminf(pd[i], d);
        }
        if (pd[i] >= 0.f) {
          unsigned long long pk = ((unsigned long long)__float_as_uint(pd[i]) << 32)
                                | (unsigned long long)(0xFFFFFFFFu - (unsigned)j);
          best = best > pk ? best : pk;
        }
      }
#pragma unroll
      for (int off = 32; off >= 1; off >>= 1) {
        unsigned long long o = __shfl_xor(best, off, 64);
        best = best > o ? best : o;
      }
      if (lane == 0) wred[p*16 + wid] = best;
      __syncthreads();
      if (wid == 0) {
        if (lane == 0) winLDS[1-p] = -1;   // safe: all waves past prev spin
        unsigned long long m = wred[p*16 + (lane & 15)];
#pragma unroll
        for (int off = 8; off >= 1; off >>= 1) {
          unsigned long long o = __shfl_xor(m, off, 64);
          m = m > o ? m : o;
        }
        if (lane == 0)
          __hip_atomic_store(&slot[it*FPSB + b], m,
                             __ATOMIC_RELAXED, __HIP_MEMORY_SCOPE_AGENT);
        unsigned long long v = 0ull;
        if (lane < FPSB) {
          const unsigned long long* sp = &slot[it*FPSB + lane];
          v = __hip_atomic_load(sp, __ATOMIC_RELAXED, __HIP_MEMORY_SCOPE_AGENT);
          while (v == 0ull)
            v = __hip_atomic_load(sp, __ATOMIC_RELAXED, __HIP_MEMORY_SCOPE_AGENT);
        }
#pragma unroll
        for (int off = 8; off >= 1; off >>= 1) {
          unsigned long long o = __shfl_xor(v, off, 64);
          v = v > o ? v : o;
        }
        v = __shfl(v, 0, 64);
        int win = (int)(0xFFFFFFFFu - (unsigned)(v & 0xFFFFFFFFull));
        if (lane == 0) {
          if (b == 0)
            __hip_atomic_store((unsigned*)&sampled[it+1], (unsigned)win,
                               __ATOMIC_RELAXED, __HIP_MEMORY_SCOPE_AGENT);
          winLDS[p] = win;
        }
        last = win;
      } else {
        int w = winLDS[p];
        while (w == -1) { __builtin_amdgcn_s_sleep(1); w = winLDS[p]; }
        last = w;
      }
    }
  } else {
    // ------------------ worker role: group + bn1 stats ------------------
    unsigned* hist  = (unsigned*)smraw;              // 8192
    unsigned* scan  = (unsigned*)(smraw + 32768);    // 1024
    unsigned* candK = (unsigned*)(smraw + 36864);    // 512
    int*      candI = (int*)(smraw + 38912);         // 512
    float*    feat  = (float*)(smraw + 40960);       // 768
    float*    cf    = (float*)(smraw + 44032);       // 8
    unsigned* ctl   = (unsigned*)(smraw + 44064);    // outcnt, candcnt
    volatile int* binfo = (volatile int*)(smraw + 44080); // B, bef, sid
    const int wkr = blockIdx.x - FPSB;               // 0..239
    for (int s = wkr; s < NSAMP; s += MEGA_BLOCKS - FPSB) {
      if (t == 0) {
        unsigned v = __hip_atomic_load((const unsigned*)&sampled[s],
                        __ATOMIC_RELAXED, __HIP_MEMORY_SCOPE_AGENT);
        while (v == 0xFFFFFFFFu) {
          __builtin_amdgcn_s_sleep(64);
          v = __hip_atomic_load((const unsigned*)&sampled[s],
                  __ATOMIC_RELAXED, __HIP_MEMORY_SCOPE_AGENT);
        }
        binfo[2] = (int)v;
        ctl[0] = 0u; ctl[1] = 0u;
      }
      for (int k = t; k < 8192; k += 1024) hist[k] = 0u;
      __syncthreads();
      const int sid = binfo[2];
      float4 c4 = xyzw[sid];
      const float cx=c4.x, cy=c4.y, cz=c4.z, c2=c4.w;
      // pass 1: histogram of monotone keys
      for (int i = 0; i < N_PTS/1024; ++i) {
        int j = i*1024 + t;
        float4 p = xyzw[j];
        float dot = __fadd_rn(__fadd_rn(__fmul_rn(cx,p.x),__fmul_rn(cy,p.y)),__fmul_rn(cz,p.z));
        float d = __fsub_rn(__fadd_rn(c2, p.w), __fmul_rn(2.0f, dot));
        unsigned kb = __float_as_uint(d);
        kb ^= ((unsigned)((int)kb >> 31)) | 0x80000000u;
        atomicAdd(&hist[kb >> 19], 1u);
      }
      __syncthreads();
      // scan 1024 chunks of 8 bins
      unsigned ch = 0u;
      for (int k = 0; k < 8; ++k) ch += hist[t*8 + k];
      scan[t] = ch;
      __syncthreads();
      for (int off = 1; off < 1024; off <<= 1) {
        unsigned vv = (t >= off) ? scan[t - off] : 0u;
        __syncthreads();
        scan[t] += vv;
        __syncthreads();
      }
      unsigned inc = scan[t], before = inc - ch;
      if (before < NGRP && inc >= NGRP) {
        unsigned c = before;
        for (int k = 0; k < 8; ++k) {
          unsigned nb = hist[t*8 + k];
          if (c + nb >= NGRP) { binfo[0] = t*8 + k; binfo[1] = (int)c; break; }
          c += nb;
        }
      }
      __syncthreads();
      const unsigned B = (unsigned)binfo[0];
      const int bef = binfo[1];
      // pass 2: emit definite members, collect boundary candidates
      for (int i = 0; i < N_PTS/1024; ++i) {
        int j = i*1024 + t;
        float4 p = xyzw[j];
        float dot = __fadd_rn(__fadd_rn(__fmul_rn(cx,p.x),__fmul_rn(cy,p.y)),__fmul_rn(cz,p.z));
        float d = __fsub_rn(__fadd_rn(c2, p.w), __fmul_rn(2.0f, dot));
        unsigned kb = __float_as_uint(d);
        kb ^= ((unsigned)((int)kb >> 31)) | 0x80000000u;
        unsigned bin = kb >> 19;
        if (bin < B) {
          unsigned pos = atomicAdd(&ctl[0], 1u);
          groups[s*NGRP + pos] = j;
        } else if (bin == B) {
          unsigned ci = atomicAdd(&ctl[1], 1u);
          if (ci < GB_CAND) { candK[ci] = kb; candI[ci] = j; }
        }
      }
      __syncthreads();
      // pass 3: exact (key, idx) rank among boundary candidates
      int M = ctl[1] < GB_CAND ? (int)ctl[1] : GB_CAND;
      int need = NGRP - bef;
      for (int c = t; c < M; c += 1024) {
        unsigned mk = candK[c]; int mi = candI[c];
        int rank = 0;
        for (int q = 0; q < M; ++q) {
          unsigned qk = candK[q];
          rank += (qk < mk || (qk == mk && candI[q] < mi)) ? 1 : 0;
        }
        if (rank < need) {
          unsigned pos = atomicAdd(&ctl[0], 1u);
          groups[s*NGRP + pos] = candI[c];
        }
      }
      __syncthreads();
      if (t == 0) {
        while (ctl[0] < NGRP) { groups[s*NGRP + ctl[0]] = 0; ctl[0]++; }
      }
      __syncthreads();
      // bn1 stats for this sample (Y1 never stored)
      if (t < DIMS) cf[t] = pts[sid*6 + t];
      __syncthreads();
      if (t < NGRP) {
        int g = groups[s*NGRP + t];
#pragma unroll
        for (int k = 0; k < DIMS; ++k) {
          float v = pts[g*6 + k];
          feat[t*12 + k] = v - cf[k];
          feat[t*12 + 6 + k] = v;
        }
      }
      __syncthreads();
      if (t < EMB) {
        float w[12];
#pragma unroll
        for (int k = 0; k < 12; ++k) w[k] = W1[k*EMB + t];
        float b = b1[t];
        float sum = 0.f, ss = 0.f;
        for (int r = 0; r < NGRP; ++r) {
          float y = b;
#pragma unroll
          for (int k = 0; k < 12; ++k) y += feat[r*12+k] * w[k];
          sum += y; ss += y*y;
        }
        atomicAdd(&gsum[t], sum);
        atomicAdd(&gss[t], ss);
      }
      __syncthreads();   // smraw reused next s
    }
  }
}

// ---------------- bn finalize: a = scale*rsqrt(var+eps), c = bias - a*mean --
__global__ __launch_bounds__(EMB) void k_finalize(const float* __restrict__ gsum,
    const float* __restrict__ gss, const float* __restrict__ scale,
    const float* __restrict__ bias, float* __restrict__ ac) {
  int c = threadIdx.x;
  float inv = 1.f / (float)ROWS;
  float mean = gsum[c] * inv;
  float var = gss[c] * inv - mean*mean;
  var = var < 0.f ? 0.f : var;
  float a = scale[c] * rsqrtf(var + EPS_BN);
  ac[c] = a; ac[EMB + c] = bias[c] - mean * a;
}

// ---------------- fused gather+GEMM1+bn1+relu+GEMM2+stats2+select-pool ------
__global__ __launch_bounds__(EMB) void k_mlp(const float* __restrict__ pts,
    const int* __restrict__ sampled, const int* __restrict__ groups,
    const float* __restrict__ W1, const float* __restrict__ b1,
    const float* __restrict__ ac1, const float* __restrict__ W2,
    const float* __restrict__ b2, const float* __restrict__ scale2,
    float* __restrict__ gsum, float* __restrict__ gss,
    float* __restrict__ y2sel) {
  const int s = blockIdx.x, t = threadIdx.x;
  extern __shared__ float sm[];
  float* feat = sm;                 // 768
  float* cf   = sm + 768;           // 8
  float* red  = sm + 776;           // 2048
  float* h1   = sm + 2824;          // 64*512
  if (t < DIMS) cf[t] = pts[sampled[s]*6 + t];
  __syncthreads();
  if (t < NGRP) {
    int g = groups[s*NGRP + t];
#pragma unroll
    for (int k = 0; k < DIMS; ++k) {
      float v = pts[g*6 + k];
      feat[t*12+k]   = v - cf[k];
      feat[t*12+6+k] = v;
    }
  }
  __syncthreads();
  {
    float w[12];
#pragma unroll
    for (int k = 0; k < 12; ++k) w[k] = W1[k*EMB + t];
    float b = b1[t], a1 = ac1[t], c1 = ac1[EMB + t];
    for (int r = 0; r < NGRP; ++r) {
      float y = b;
#pragma unroll
      for (int k = 0; k < 12; ++k) y += feat[r*12+k] * w[k];
      float hv = a1*y + c1;
      h1[r*EMB + t] = hv > 0.f ? hv : 0.f;
    }
  }
  __syncthreads();
  const int lane = t & 63, wid = t >> 6;
  float acc[8][8];
  {
    float4 blo = *(const float4*)&b2[lane*8];
    float4 bhi = *(const float4*)&b2[lane*8 + 4];
    float b2r[8] = {blo.x, blo.y, blo.z, blo.w, bhi.x, bhi.y, bhi.z, bhi.w};
#pragma unroll
    for (int i = 0; i < 8; ++i)
#pragma unroll
      for (int j = 0; j < 8; ++j) acc[i][j] = b2r[j];
  }
  const float* h1r = h1 + (wid*8)*EMB;
  for (int k = 0; k < EMB; ++k) {
    float4 wlo = *(const float4*)&W2[k*EMB + lane*8];
    float4 whi = *(const float4*)&W2[k*EMB + lane*8 + 4];
    float wv[8] = {wlo.x, wlo.y, wlo.z, wlo.w, whi.x, whi.y, whi.z, whi.w};
    float hv[8];
#pragma unroll
    for (int i = 0; i < 8; ++i) hv[i] = h1r[i*EMB + k];
#pragma unroll
    for (int i = 0; i < 8; ++i)
#pragma unroll
      for (int j = 0; j < 8; ++j) acc[i][j] += hv[i] * wv[j];
  }
  float psum[8], pss[8], pmax[8], pmin[8];
#pragma unroll
  for (int j = 0; j < 8; ++j) {
    float sv=0.f, ssv=0.f, mx=-__builtin_inff(), mn=__builtin_inff();
#pragma unroll
    for (int i = 0; i < 8; ++i) {
      float v = acc[i][j];
      sv += v; ssv += v*v;
      mx = fmaxf(mx, v); mn = fminf(mn, v);
    }
    psum[j]=sv; pss[j]=ssv; pmax[j]=mx; pmin[j]=mn;
  }
  float* rsum = red; float* rss = red+512; float* rmx = red+1024; float* rmn = red+1536;
  for (int w = 0; w < 8; ++w) {
    if (wid == w) {
#pragma unroll
      for (int j = 0; j < 8; ++j) {
        int c = lane*8 + j;
        if (w == 0) { rsum[c]=psum[j]; rss[c]=pss[j]; rmx[c]=pmax[j]; rmn[c]=pmin[j]; }
        else { rsum[c]+=psum[j]; rss[c]+=pss[j];
               rmx[c]=fmaxf(rmx[c],pmax[j]); rmn[c]=fminf(rmn[c],pmin[j]); }
      }
    }
    __syncthreads();
  }
  atomicAdd(&gsum[t], rsum[t]);
  atomicAdd(&gss[t], rss[t]);
  y2sel[s*EMB + t] = (scale2[t] >= 0.f) ? rmx[t] : rmn[t];
}

// ---------------- epilogue: bn2+relu on pooled extremum ---------------------
__global__ __launch_bounds__(256) void k_out(const float* __restrict__ y2sel,
    const float* __restrict__ ac2, float* __restrict__ out) {
  int i = blockIdx.x*256 + threadIdx.x;
  int c = i & (EMB-1);
  float a = ac2[c], cc = ac2[EMB + c];
  float v = a*y2sel[i] + cc;
  out[i] = v > 0.f ? v : 0.f;
}

extern "C" void kernel_launch(void* const* d_in, const int* in_sizes, int n_in,
                              void* d_out, int out_size, void* d_ws, size_t ws_size,
                              hipStream_t stream) {
  const float* pts    = (const float*)d_in[0];
  const float* W1     = (const float*)d_in[1];
  const float* b1     = (const float*)d_in[2];
  const float* scale1 = (const float*)d_in[3];
  const float* bias1  = (const float*)d_in[4];
  const float* W2     = (const float*)d_in[5];
  const float* b2     = (const float*)d_in[6];
  const float* scale2 = (const float*)d_in[7];
  const float* bias2  = (const float*)d_in[8];
  const int*   seed   = (const int*)d_in[9];
  float* out = (float*)d_out;

  char* ws = (char*)d_ws;
  int*    sampled = (int*)(ws);
  int*    groups  = (int*)(ws + 8192);
  float4* xyzw    = (float4*)(ws + 532480);
  float*  stats   = (float*)(ws + 1581056);
  float* gsum1 = stats, *gss1 = stats+512, *gsum2 = stats+1024, *gss2 = stats+1536;
  float*  ac1     = (float*)(ws + 1589248);
  float*  ac2     = (float*)(ws + 1593344);
  float*  y2sel   = (float*)(ws + 1597440);
  // slot aliases y2sel (disjoint lifetime): 2047*16 u64 = 262KB < 4MB region
  unsigned long long* slot = (unsigned long long*)(ws + 1597440);

  k_init<<<256, 256, 0, stream>>>(pts, seed, slot, stats, xyzw, sampled);
  k_mega<<<MEGA_BLOCKS, 1024, 0, stream>>>(xyzw, pts, W1, b1, slot, sampled,
                                           groups, gsum1, gss1);
  k_finalize<<<1, EMB, 0, stream>>>(gsum1, gss1, scale1, bias1, ac1);
  size_t mlp_lds = (size_t)(2824 + 64*EMB) * sizeof(float);
  k_mlp<<<NSAMP, EMB, mlp_lds, stream>>>(pts, sampled, groups, W1, b1, ac1,
                                         W2, b2, scale2, gsum2, gss2, y2sel);
  k_finalize<<<1, EMB, 0, stream>>>(gsum2, gss2, scale2, bias2, ac2);
  k_out<<<(out_size+255)/256, 256, 0, stream>>>(y2sel, ac2, out);
}